// Round 3
// baseline (122.415 us; speedup 1.0000x reference)
//
#include <hip/hip_runtime.h>
#include <hip/hip_bf16.h>
#include <cstdint>
#include <cstddef>

typedef float  f32x4  __attribute__((ext_vector_type(4)));
typedef __bf16 bf16x8 __attribute__((ext_vector_type(8)));
typedef __bf16 bf16x4 __attribute__((ext_vector_type(4)));

#define MFMA(a, b, c) __builtin_amdgcn_mfma_f32_16x16x32_bf16((a), (b), (c), 0, 0, 0)

#define B_     8
#define S_     2048
#define D_     1024
#define E_     64
#define YSZ    (B_ * S_ * D_)   // 16777216
#define KTR    16               // truncation depth: rho^16 ~ 2e-7

// ---------------- k_setup: convert weights to bf16 ----------------
__global__ __launch_bounds__(256) void k_setup(const float* __restrict__ w_in,
                                               const float* __restrict__ w_out,
                                               __bf16* __restrict__ winb,
                                               __bf16* __restrict__ wob) {
  const int i = blockIdx.x * 256 + threadIdx.x;
  winb[i] = (__bf16)w_in[i];
  wob[i]  = (__bf16)w_out[i];
}

// ---------------- k_bi: beta GEMM (blocks 0..255)  ||  impulse (block 256) ----------------
// beta blocks: beta_bf = bf16(x @ w_in^T), 64 rows/block, validated k_beta machinery.
// impulse block: 4 waves = 16 impulse columns each; produces Gt (conv B-operand) and
// CkT transposed ([k][e][f], f contiguous) for the coalesced final-state reduction.
__global__ __launch_bounds__(256) void k_bi(const float* __restrict__ x,
                                            const __bf16* __restrict__ winb,
                                            const float* __restrict__ resonance,
                                            const float* __restrict__ alpha,
                                            const float* __restrict__ omega,
                                            __bf16* __restrict__ beta_bf,
                                            __bf16* __restrict__ Gt,
                                            float* __restrict__ CkTR,
                                            float* __restrict__ CkTI) {
  __shared__ __bf16 lsr[4][16][72];
  __shared__ __bf16 lsi[4][16][72];

  const int tid = threadIdx.x;
  const int w = tid >> 6, lane = tid & 63;
  const int u = lane >> 4, fl = lane & 15;

  if (blockIdx.x < 256) {
    // ---- beta GEMM ----
    const int rowA = blockIdx.x * 64 + w * 16 + fl;
    const float*  xp = x + (size_t)rowA * 1024 + u * 8;
    const __bf16* wp = winb + fl * 1024 + u * 8;

    f32x4  acc[4] = {};
    f32x4  xc[2][2], xn[2][2];
    bf16x8 bc[4][2], bn[4][2];

#pragma unroll
    for (int kt = 0; kt < 2; kt++) {
      xc[kt][0] = *(const f32x4*)(xp + kt * 32);
      xc[kt][1] = *(const f32x4*)(xp + kt * 32 + 4);
    }
#pragma unroll
    for (int ct = 0; ct < 4; ct++)
#pragma unroll
      for (int kt = 0; kt < 2; kt++)
        bc[ct][kt] = *(const bf16x8*)(wp + ct * 16384 + kt * 32);

#pragma unroll
    for (int kk = 0; kk < 16; kk++) {
      if (kk < 15) {
        const int k1 = (kk + 1) * 64;
#pragma unroll
        for (int kt = 0; kt < 2; kt++) {
          xn[kt][0] = *(const f32x4*)(xp + k1 + kt * 32);
          xn[kt][1] = *(const f32x4*)(xp + k1 + kt * 32 + 4);
        }
#pragma unroll
        for (int ct = 0; ct < 4; ct++)
#pragma unroll
          for (int kt = 0; kt < 2; kt++)
            bn[ct][kt] = *(const bf16x8*)(wp + ct * 16384 + k1 + kt * 32);
      }
      bf16x8 af[2];
#pragma unroll
      for (int kt = 0; kt < 2; kt++)
#pragma unroll
        for (int j = 0; j < 4; j++) {
          af[kt][j]     = (__bf16)xc[kt][0][j];
          af[kt][j + 4] = (__bf16)xc[kt][1][j];
        }
#pragma unroll
      for (int ct = 0; ct < 4; ct++) {
        acc[ct] = MFMA(af[0], bc[ct][0], acc[ct]);
        acc[ct] = MFMA(af[1], bc[ct][1], acc[ct]);
      }
      if (kk < 15) {
#pragma unroll
        for (int kt = 0; kt < 2; kt++) { xc[kt][0] = xn[kt][0]; xc[kt][1] = xn[kt][1]; }
#pragma unroll
        for (int ct = 0; ct < 4; ct++) { bc[ct][0] = bn[ct][0]; bc[ct][1] = bn[ct][1]; }
      }
    }

    const int rowC = blockIdx.x * 64 + w * 16 + u * 4;
#pragma unroll
    for (int ct = 0; ct < 4; ct++)
#pragma unroll
      for (int r = 0; r < 4; r++)
        beta_bf[(size_t)(rowC + r) * 64 + ct * 16 + fl] = (__bf16)acc[ct][r];
    return;
  }

  // ---- impulse responses: C_k = R(LambdaR)^k ----
  const int ecol = w * 16 + fl;   // wave w owns impulse columns w*16..w*16+15

  bf16x8 afr[4][2];   // A[f][e] = R[e][f] - (e==f)
#pragma unroll
  for (int mt = 0; mt < 4; mt++)
#pragma unroll
    for (int kt = 0; kt < 2; kt++)
#pragma unroll
      for (int j = 0; j < 8; j++) {
        const int e = kt * 32 + u * 8 + j;
        const int f = mt * 16 + fl;
        float v = resonance[e * 64 + f];
        if (e == f) v -= 1.0f;
        afr[mt][kt][j] = (__bf16)v;
      }

  float mcv[4][4], msv[4][4];
#pragma unroll
  for (int mt = 0; mt < 4; mt++)
#pragma unroll
    for (int r = 0; r < 4; r++) {
      const int fr = mt * 16 + u * 4 + r;
      const float mg = 1.0f / (1.0f + expf(-alpha[fr]));
      mcv[mt][r] = mg * cosf(omega[fr]);
      msv[mt][r] = mg * sinf(omega[fr]);
    }

  f32x4 sr[4] = {}, si[4] = {};

  for (int s = 0; s < KTR; s++) {
    f32x4 rr[4], ri[4];
#pragma unroll
    for (int mt = 0; mt < 4; mt++)
#pragma unroll
      for (int r = 0; r < 4; r++) {
        const float bt = (s == 0 && (mt * 16 + u * 4 + r) == ecol) ? 1.0f : 0.0f;
        rr[mt][r] = mcv[mt][r] * sr[mt][r] - msv[mt][r] * si[mt][r] + bt;
        ri[mt][r] = msv[mt][r] * sr[mt][r] + mcv[mt][r] * si[mt][r];
      }
#pragma unroll
    for (int mt = 0; mt < 4; mt++) {
      bf16x4 pr, pi;
#pragma unroll
      for (int r = 0; r < 4; r++) { pr[r] = (__bf16)rr[mt][r]; pi[r] = (__bf16)ri[mt][r]; }
      *(bf16x4*)&lsr[w][fl][mt * 16 + u * 4] = pr;
      *(bf16x4*)&lsi[w][fl][mt * 16 + u * 4] = pi;
    }
    __syncthreads();
    bf16x8 brf[2], bif[2];
#pragma unroll
    for (int kt = 0; kt < 2; kt++) {
      brf[kt] = *(const bf16x8*)&lsr[w][fl][kt * 32 + u * 8];
      bif[kt] = *(const bf16x8*)&lsi[w][fl][kt * 32 + u * 8];
    }
#pragma unroll
    for (int mt = 0; mt < 4; mt++) {
      f32x4 dr = MFMA(afr[mt][0], brf[0], rr[mt]);
      sr[mt]   = MFMA(afr[mt][1], brf[1], dr);
      f32x4 di = MFMA(afr[mt][0], bif[0], ri[mt]);
      si[mt]   = MFMA(afr[mt][1], bif[1], di);
    }
    // state now equals C_s; store (Gt for conv, CkT transposed for fin)
#pragma unroll
    for (int mt = 0; mt < 4; mt++)
#pragma unroll
      for (int r = 0; r < 4; r++) {
        const int f = mt * 16 + u * 4 + r;
        Gt[f * 1024 + s * 64 + ecol]    = (__bf16)sr[mt][r];
        CkTR[s * 4096 + ecol * 64 + f]  = sr[mt][r];
        CkTI[s * 4096 + ecol * 64 + f]  = si[mt][r];
      }
    __syncthreads();
  }
}

// ---------------- k_cy: conv (states via LDS) + y GEMM + LayerNorm + fin ----------------
// 512 blocks x 256 thr; block owns 32 seq rows x full D=1024.
// Phase 1: states[32][64] = sum_k beta[t-k] @ G_k  (waves split 2 row-tiles x 2 col-halves)
// Phase 2: y = states @ w_out^T + LN (validated k_y, A-frags from LDS)
// Tail blocks (blockIdx%64==63): wave 0 computes r_fin/i_fin via coalesced CkT reads.
__global__ __launch_bounds__(256) void k_cy(const __bf16* __restrict__ beta_bf,
                                            const __bf16* __restrict__ Gt,
                                            const __bf16* __restrict__ wob,
                                            const float* __restrict__ gamma,
                                            const float* __restrict__ lbeta,
                                            const float* __restrict__ CkTR,
                                            const float* __restrict__ CkTI,
                                            float* __restrict__ y) {
  __shared__ __bf16 st[32][72];   // states tile, 144-B row stride: 16B-aligned, 2-way banks
  __shared__ float pS1[4][32];
  __shared__ float pS2[4][32];

  const int tid = threadIdx.x;
  const int w = tid >> 6, lane = tid & 63;
  const int u = lane >> 4, fl = lane & 15;
  const int rowbase = blockIdx.x * 32;

  // ---- phase 1: conv ----
  {
    const int rw = w & 1, cw = w >> 1;
    const int rowA = rowbase + rw * 16 + fl;
    const int tloc = rowA & (S_ - 1);
    const __bf16* xp = beta_bf + (size_t)rowA * 64 + u * 8;
    const __bf16* gp = Gt + (size_t)(cw * 32 + fl) * 1024 + u * 8;
    const bf16x8 ZB = {};

    f32x4  acc[2] = {};
    bf16x8 ac[2], an[2], bc[2][2], bn[2][2];

#pragma unroll
    for (int kt = 0; kt < 2; kt++) ac[kt] = *(const bf16x8*)(xp + kt * 32);
#pragma unroll
    for (int ct = 0; ct < 2; ct++)
#pragma unroll
      for (int kt = 0; kt < 2; kt++)
        bc[ct][kt] = *(const bf16x8*)(gp + ct * 16384 + kt * 32);

#pragma unroll
    for (int kk = 0; kk < 16; kk++) {
      if (kk < 15) {
        const int k1 = kk + 1;
        const bool ok = (tloc >= k1);
        const __bf16* ap = xp - (ok ? k1 * 64 : 0);
#pragma unroll
        for (int kt = 0; kt < 2; kt++) {
          bf16x8 v = *(const bf16x8*)(ap + kt * 32);
          an[kt] = ok ? v : ZB;
        }
#pragma unroll
        for (int ct = 0; ct < 2; ct++)
#pragma unroll
          for (int kt = 0; kt < 2; kt++)
            bn[ct][kt] = *(const bf16x8*)(gp + ct * 16384 + k1 * 64 + kt * 32);
      }
#pragma unroll
      for (int ct = 0; ct < 2; ct++) {
        acc[ct] = MFMA(ac[0], bc[ct][0], acc[ct]);
        acc[ct] = MFMA(ac[1], bc[ct][1], acc[ct]);
      }
      if (kk < 15) {
        ac[0] = an[0]; ac[1] = an[1];
#pragma unroll
        for (int ct = 0; ct < 2; ct++) { bc[ct][0] = bn[ct][0]; bc[ct][1] = bn[ct][1]; }
      }
    }
    // write states tile to LDS
#pragma unroll
    for (int ct = 0; ct < 2; ct++)
#pragma unroll
      for (int r = 0; r < 4; r++)
        st[rw * 16 + u * 4 + r][cw * 32 + ct * 16 + fl] = (__bf16)acc[ct][r];
  }
  __syncthreads();

  // ---- phase 2: y = states @ w_out^T + LN ----
  bf16x8 ar[2][2];
#pragma unroll
  for (int rt = 0; rt < 2; rt++)
#pragma unroll
    for (int kt = 0; kt < 2; kt++)
      ar[rt][kt] = *(const bf16x8*)&st[rt * 16 + fl][kt * 32 + u * 8];

  const __bf16* wp = wob + (size_t)(w * 256 + fl) * 64 + u * 8;

  f32x4 acc[2][16] = {};
  bf16x8 bcur[2], bnext[2];
#pragma unroll
  for (int kt = 0; kt < 2; kt++) bcur[kt] = *(const bf16x8*)(wp + kt * 32);

#pragma unroll
  for (int ct = 0; ct < 16; ct++) {
    if (ct < 15) {
#pragma unroll
      for (int kt = 0; kt < 2; kt++) bnext[kt] = *(const bf16x8*)(wp + (ct + 1) * 1024 + kt * 32);
    }
#pragma unroll
    for (int rt = 0; rt < 2; rt++) {
      acc[rt][ct] = MFMA(ar[rt][0], bcur[0], acc[rt][ct]);
      acc[rt][ct] = MFMA(ar[rt][1], bcur[1], acc[rt][ct]);
    }
    if (ct < 15) { bcur[0] = bnext[0]; bcur[1] = bnext[1]; }
  }

  float s1[2][4], s2[2][4];
#pragma unroll
  for (int rt = 0; rt < 2; rt++)
#pragma unroll
    for (int r = 0; r < 4; r++) {
      float a = 0.f, q = 0.f;
#pragma unroll
      for (int ct = 0; ct < 16; ct++) {
        const float v = acc[rt][ct][r];
        a += v; q += v * v;
      }
      s1[rt][r] = a; s2[rt][r] = q;
    }
#pragma unroll
  for (int m = 1; m < 16; m <<= 1) {
#pragma unroll
    for (int rt = 0; rt < 2; rt++)
#pragma unroll
      for (int r = 0; r < 4; r++) {
        s1[rt][r] += __shfl_xor(s1[rt][r], m, 64);
        s2[rt][r] += __shfl_xor(s2[rt][r], m, 64);
      }
  }
  if (fl == 0) {
#pragma unroll
    for (int rt = 0; rt < 2; rt++)
#pragma unroll
      for (int r = 0; r < 4; r++) {
        pS1[w][rt * 16 + u * 4 + r] = s1[rt][r];
        pS2[w][rt * 16 + u * 4 + r] = s2[rt][r];
      }
  }
  __syncthreads();
  float mu[2][4], rs[2][4];
#pragma unroll
  for (int rt = 0; rt < 2; rt++)
#pragma unroll
    for (int r = 0; r < 4; r++) {
      const int rl = rt * 16 + u * 4 + r;
      float S1 = 0.f, S2 = 0.f;
#pragma unroll
      for (int ww = 0; ww < 4; ww++) { S1 += pS1[ww][rl]; S2 += pS2[ww][rl]; }
      const float m  = S1 * (1.0f / 1024.0f);
      const float va = S2 * (1.0f / 1024.0f) - m * m;
      mu[rt][r] = m;
      rs[rt][r] = rsqrtf(va + 1e-5f);
    }
#pragma unroll
  for (int ct = 0; ct < 16; ct++) {
    const int d = w * 256 + ct * 16 + fl;
    const float gv = gamma[d], bv = lbeta[d];
#pragma unroll
    for (int rt = 0; rt < 2; rt++)
#pragma unroll
      for (int r = 0; r < 4; r++) {
        const float v = (acc[rt][ct][r] - mu[rt][r]) * rs[rt][r] * gv + bv;
        y[(size_t)(rowbase + rt * 16 + u * 4 + r) * 1024 + d] = v;
      }
  }

  // ---- fin: r_fin/i_fin for tail blocks (coalesced CkT reads) ----
  if ((blockIdx.x & 63) == 63 && tid < 64) {
    const int b = blockIdx.x >> 6;
    const int f = tid;
    float aR = 0.f, aI = 0.f;
#pragma unroll
    for (int k = 0; k < KTR; k++) {
      const __bf16* br = beta_bf + (size_t)(b * S_ + (S_ - 1) - k) * 64;
      const float* cR = CkTR + k * 4096 + f;
      const float* cI = CkTI + k * 4096 + f;
#pragma unroll
      for (int e = 0; e < 64; e += 4) {
        const float b0 = (float)br[e],     b1 = (float)br[e + 1];
        const float b2 = (float)br[e + 2], b3 = (float)br[e + 3];
        aR += b0 * cR[e * 64] + b1 * cR[(e + 1) * 64] + b2 * cR[(e + 2) * 64] + b3 * cR[(e + 3) * 64];
        aI += b0 * cI[e * 64] + b1 * cI[(e + 1) * 64] + b2 * cI[(e + 2) * 64] + b3 * cI[(e + 3) * 64];
      }
    }
    y[YSZ + b * 64 + f]       = aR;
    y[YSZ + 512 + b * 64 + f] = aI;
  }
}

extern "C" void kernel_launch(void* const* d_in, const int* in_sizes, int n_in,
                              void* d_out, int out_size, void* d_ws, size_t ws_size,
                              hipStream_t stream) {
  const float* x         = (const float*)d_in[0];
  const float* alpha     = (const float*)d_in[1];
  const float* omega     = (const float*)d_in[2];
  const float* w_in      = (const float*)d_in[3];
  const float* w_out     = (const float*)d_in[4];
  const float* resonance = (const float*)d_in[5];
  const float* ln_g      = (const float*)d_in[6];
  const float* ln_b      = (const float*)d_in[7];
  float* out = (float*)d_out;

  char* ws = (char*)d_ws;
  __bf16* beta_bf = (__bf16*)ws;                                   // 2 MB
  __bf16* winb    = (__bf16*)(ws + (2u << 20));                    // 128 KB
  __bf16* wob     = (__bf16*)(ws + (2u << 20) + (128u << 10));     // 128 KB
  __bf16* Gt      = (__bf16*)(ws + (2u << 20) + (256u << 10));     // 128 KB
  float*  CkTR    = (float*) (ws + (2u << 20) + (384u << 10));     // 256 KB
  float*  CkTI    = (float*) (ws + (2u << 20) + (640u << 10));     // 256 KB

  k_setup<<<256, 256, 0, stream>>>(w_in, w_out, winb, wob);
  k_bi   <<<257, 256, 0, stream>>>(x, winb, resonance, alpha, omega,
                                   beta_bf, Gt, CkTR, CkTI);
  k_cy   <<<512, 256, 0, stream>>>(beta_bf, Gt, wob, ln_g, ln_b, CkTR, CkTI, out);
}